// Round 2
// baseline (10364.240 us; speedup 1.0000x reference)
//
#include <hip/hip_runtime.h>

#define LSEQ 2048
#define NB 24
#define NH 75
#define G3 225
#define NIN 500
#define OUTW 450

typedef _Float16 h2 __attribute__((ext_vector_type(2)));
typedef _Float16 h8 __attribute__((ext_vector_type(8)));
typedef float f4 __attribute__((ext_vector_type(4)));

// cvt_pkrtz returns __fp16-based vec2 on this clang; bit-cast to _Float16 vec2
__device__ __forceinline__ h2 pkrtz(float a, float b) {
  return __builtin_bit_cast(h2, __builtin_amdgcn_cvt_pkrtz(a, b));
}

__device__ __forceinline__ float dot2(h2 a, h2 b, float c) {
#if __has_builtin(__builtin_amdgcn_fdot2)
  return __builtin_amdgcn_fdot2(a, b, c, false);
#else
  return c + (float)a[0] * (float)b[0] + (float)a[1] * (float)b[1];
#endif
}

__device__ __forceinline__ float sigm(float x) {
  return __builtin_amdgcn_rcpf(1.f + __builtin_amdgcn_exp2f(-1.4426950408889634f * x));
}
__device__ __forceinline__ float tanh_f(float x) {
  float xx = fminf(x, 15.f);
  float e = __builtin_amdgcn_exp2f(2.8853900817779268f * xx);
  return (e - 1.f) * __builtin_amdgcn_rcpf(e + 1.f);
}

// ---------------- init: zero the progress flags in d_ws ----------------
__global__ void init_flags(int* f) {
  if (threadIdx.x < 144) f[threadIdx.x] = 0;
}

// ---------------- kernel A: gx = x @ w_ih0^T + b_ih0, f16-packed into out cols [225:450) ----
// M = 49152 (t*24+b), N = 450 (dir*225+g), K = 500. NT GEMM, f16 MFMA 16x16x32.
__device__ __forceinline__ void load8_guard(float* v, const float* src, int kbase, bool rowvalid) {
  if (rowvalid && (kbase + 8 <= NIN)) {
    f4 t0 = *(const f4*)(src);
    f4 t1 = *(const f4*)(src + 4);
    v[0] = t0[0]; v[1] = t0[1]; v[2] = t0[2]; v[3] = t0[3];
    v[4] = t1[0]; v[5] = t1[1]; v[6] = t1[2]; v[7] = t1[3];
  } else {
#pragma unroll
    for (int i = 0; i < 8; i++) v[i] = (rowvalid && (kbase + i < NIN)) ? src[i] : 0.f;
  }
}

__device__ __forceinline__ void pack8_store(_Float16* dst, const float* v) {
  h2 a = pkrtz(v[0], v[1]);
  h2 b = pkrtz(v[2], v[3]);
  h2 c = pkrtz(v[4], v[5]);
  h2 d = pkrtz(v[6], v[7]);
  h8 o;
  o[0] = a[0]; o[1] = a[1]; o[2] = b[0]; o[3] = b[1];
  o[4] = c[0]; o[5] = c[1]; o[6] = d[0]; o[7] = d[1];
  *(h8*)dst = o;
}

__global__ __launch_bounds__(256) void gemm_gx(const float* __restrict__ x,
                                               const float* __restrict__ w,
                                               const float* __restrict__ bias,
                                               float* __restrict__ out) {
  __shared__ __align__(16) _Float16 xs[64 * 40];    // [m][k] rows padded to 40 halves
  __shared__ __align__(16) _Float16 wsh[464 * 40];  // [n][k] rows padded

  const int tid = threadIdx.x;
  const int blk = blockIdx.x;
  const int lane = tid & 63, wid = tid >> 6;
  const int q = lane >> 4, cn = lane & 15;
  const int r = tid >> 2, kq = tid & 3;

  f4 acc[29];
#pragma unroll
  for (int j = 0; j < 29; j++) acc[j] = f4{0.f, 0.f, 0.f, 0.f};

  for (int kc = 0; kc < 16; kc++) {
    const int k0 = kc * 32;
    const int kbase = k0 + kq * 8;
    // stage x tile (64 rows x 32 k)
    {
      const float* src = x + (size_t)(blk * 64 + r) * NIN + kbase;
      float v[8];
      load8_guard(v, src, kbase, true);
      pack8_store(&xs[r * 40 + kq * 8], v);
    }
    // stage w tile (464 padded rows x 32 k)
#pragma unroll
    for (int it = 0; it < 8; it++) {
      int rr = r + it * 64;
      if (rr < 464) {
        const float* src = w + (size_t)rr * NIN + kbase;
        float v[8];
        load8_guard(v, src, kbase, rr < OUTW);
        pack8_store(&wsh[rr * 40 + kq * 8], v);
      }
    }
    __syncthreads();
    h8 a = *(const h8*)&xs[(wid * 16 + cn) * 40 + q * 8];
#pragma unroll
    for (int j = 0; j < 29; j++) {
      h8 bf = *(const h8*)&wsh[(j * 16 + cn) * 40 + q * 8];
      acc[j] = __builtin_amdgcn_mfma_f32_16x16x32_f16(a, bf, acc[j], 0, 0, 0);
    }
    __syncthreads();
  }

  // epilogue: +bias, f16-pack adjacent n pairs, store into out cols [225:450)
#pragma unroll
  for (int j = 0; j < 29; j++) {
    int n = j * 16 + cn;
    float bv = (n < OUTW) ? bias[n] : 0.f;
#pragma unroll
    for (int rr = 0; rr < 4; rr++) {
      float val = acc[j][rr] + bv;
      float partner = __shfl_xor(val, 1, 64);
      if (((lane & 1) == 0) && n < OUTW) {
        h2 pk = pkrtz(val, partner);
        int mg = blk * 64 + wid * 16 + q * 4 + rr;
        out[(size_t)mg * OUTW + G3 + (n >> 1)] = __builtin_bit_cast(float, pk);
      }
    }
  }
}

// ---------------- kernel B: pipelined persistent GRU scan ----------------
// 144 real WGs = cell (0..5) x batch (0..23), block id = c*24+b so a batch's
// 6 cells land on one XCD under round-robin block->XCD mapping (24%8==0).
// Weights live in VGPRs (f16 pairs). thread g<225 owns gate-row g.
// Cross-cell handoff: h written to d_out (also the final output), published via
// agent-scope flags; consumers prefetch with lag 2 using the 31 spare lanes.
__device__ __forceinline__ void wait_flags(int* flags, int i0, int i1, int want) {
  while (__hip_atomic_load(&flags[i0], __ATOMIC_ACQUIRE, __HIP_MEMORY_SCOPE_AGENT) < want ||
         __hip_atomic_load(&flags[i1], __ATOMIC_ACQUIRE, __HIP_MEMORY_SCOPE_AGENT) < want)
    __builtin_amdgcn_s_sleep(2);
}

__global__ __launch_bounds__(256, 1) void scan_gru(
    const float* __restrict__ h0,
    const float* __restrict__ w_hh0, const float* __restrict__ b_hh0,
    const float* __restrict__ w_ih12, const float* __restrict__ w_hh12,
    const float* __restrict__ b_ih12, const float* __restrict__ b_hh12,
    float* __restrict__ out, int* flags, const float* __restrict__ guard) {
  // big static pad discourages 2 WGs/CU (total ~60KB, <64KB per-WG limit)
  __shared__ char occ_pad[56 * 1024];
  __shared__ float A_s[G3], B_s[G3];
  __shared__ __align__(16) _Float16 h16[NH + 1];
  __shared__ __align__(16) _Float16 x16r[4][152];

  const int bi = blockIdx.x;
  if (bi >= 144) return;  // dummy blocks (grid overshoot keeps 1 WG/CU likely)
  const int tid = threadIdx.x;
  // keep occ_pad alive without provable side effects
  if (guard == nullptr) occ_pad[tid] = (char)tid;

  const int c = bi / NB, b = bi % NB;
  const int l = c >> 1, d = c & 1;
  const int g = tid;
  const bool isg = tid < G3;
  const int u0 = (l - 1) * 2;  // upstream cell pair (valid for l>=1)

  h2 whh_r[38];
  h2 wih_r[75];
  float bhh_g = 0.f, bih_g = 0.f;

  if (isg) {
    const float* whh = (l == 0) ? (w_hh0 + (size_t)(d * G3 + g) * NH)
                                : (w_hh12 + (size_t)(((l - 1) * 2 + d) * G3 + g) * NH);
#pragma unroll
    for (int kk = 0; kk < 37; kk++)
      whh_r[kk] = pkrtz(whh[2 * kk], whh[2 * kk + 1]);
    whh_r[37] = pkrtz(whh[74], 0.f);
    bhh_g = (l == 0) ? b_hh0[d * G3 + g] : b_hh12[((l - 1) * 2 + d) * G3 + g];
    if (l > 0) {
      const float* wih = w_ih12 + (size_t)(((l - 1) * 2 + d) * G3 + g) * (2 * NH);
#pragma unroll
      for (int kk = 0; kk < 75; kk++)
        wih_r[kk] = pkrtz(wih[2 * kk], wih[2 * kk + 1]);
      bih_g = b_ih12[((l - 1) * 2 + d) * G3 + g];
    }
  }

  float hreg = 0.f;
  if (tid < NH) {
    hreg = h0[(size_t)(c * NB + b) * NH + tid];
    h16[tid] = (_Float16)hreg;
  }
  if (tid == 0) h16[NH] = (_Float16)0.f;

  // prologue: fetch upstream x for t=0,1 (layers 1-2)
  if (l >= 1) {
    for (int p = 0; p < 2; p++) {
      if (tid == 0) wait_flags(flags, u0 * NB + b, (u0 + 1) * NB + b, p + 1);
      __syncthreads();
      if (tid < NH) {
        const float* rp = out + ((size_t)p * NB + b) * OUTW + u0 * NH;
        ((h2*)x16r[p])[tid] = pkrtz(rp[2 * tid], rp[2 * tid + 1]);
      }
    }
  }
  // layer-0: preload gx(t=0) (f16-packed by gemm_gx at cols [225:450))
  float gx_cur = 0.f, gx_next = 0.f;
  if (l == 0 && isg) {
    int n = d * G3 + g;
    float s = out[(size_t)b * OUTW + G3 + (n >> 1)];
    h2 hh = __builtin_bit_cast(h2, s);
    gx_cur = (n & 1) ? (float)hh[1] : (float)hh[0];
  }
  __syncthreads();

  for (int t = 0; t < LSEQ; t++) {
    float* orow = out + ((size_t)t * NB + b) * OUTW;
    if (isg) {
      // h-side preactivation (recurrent dot, h from previous step)
      const h2* hh2 = (const h2*)h16;
      float s0 = 0.f, s1 = 0.f;
#pragma unroll
      for (int kk = 0; kk < 38; kk += 2) {
        s0 = dot2(whh_r[kk], hh2[kk], s0);
        s1 = dot2(whh_r[kk + 1], hh2[kk + 1], s1);
      }
      float accB = bhh_g + s0 + s1;
      float accA;
      if (l == 0) {
        accA = gx_cur;
      } else {
        const h2* xx2 = (const h2*)x16r[t & 3];
        float a0 = 0.f, a1 = 0.f, a2 = 0.f, a3 = 0.f;
#pragma unroll
        for (int kk = 0; kk < 72; kk += 4) {
          a0 = dot2(wih_r[kk], xx2[kk], a0);
          a1 = dot2(wih_r[kk + 1], xx2[kk + 1], a1);
          a2 = dot2(wih_r[kk + 2], xx2[kk + 2], a2);
          a3 = dot2(wih_r[kk + 3], xx2[kk + 3], a3);
        }
        a0 = dot2(wih_r[72], xx2[72], a0);
        a1 = dot2(wih_r[73], xx2[73], a1);
        a2 = dot2(wih_r[74], xx2[74], a2);
        accA = bih_g + (a0 + a1) + (a2 + a3);
      }
      A_s[g] = accA;
      B_s[g] = accB;
    }
    // layer-0: prefetch next step's gx while gates settle
    if (l == 0 && isg && (t + 1 < LSEQ)) {
      int n = d * G3 + g;
      float s = out[((size_t)(t + 1) * NB + b) * OUTW + G3 + (n >> 1)];
      h2 hh = __builtin_bit_cast(h2, s);
      gx_next = (n & 1) ? (float)hh[1] : (float)hh[0];
    }
    __syncthreads();  // gates visible

    if (tid < NH) {
      int j = tid;
      float rg = sigm(A_s[j] + B_s[j]);
      float zg = sigm(A_s[NH + j] + B_s[NH + j]);
      float ng = tanh_f(A_s[2 * NH + j] + rg * B_s[2 * NH + j]);
      float hn = (1.f - zg) * ng + zg * hreg;
      hreg = hn;
      h16[j] = (_Float16)hn;
      orow[c * NH + j] = hn;
    } else if (l >= 1 && tid >= G3) {
      // spare lanes: lag-2 prefetch of upstream h into the x ring
      int tt = t + 2;
      if (tt < LSEQ) {
        if (tid == G3) wait_flags(flags, u0 * NB + b, (u0 + 1) * NB + b, tt + 1);
        const float* rp = out + ((size_t)tt * NB + b) * OUTW + u0 * NH;
        int i0 = (tid - G3) * 5;
#pragma unroll
        for (int qq = 0; qq < 5; qq++) {
          int k = i0 + qq;
          if (k < 2 * NH) x16r[tt & 3][k] = (_Float16)rp[k];
        }
      }
    }
    __syncthreads();  // h16 + out stores drained (per-wave vmcnt before barrier)

    if (tid == 0 && c < 4)
      __hip_atomic_store(&flags[bi], t + 1, __ATOMIC_RELEASE, __HIP_MEMORY_SCOPE_AGENT);
    gx_cur = gx_next;
  }
}

extern "C" void kernel_launch(void* const* d_in, const int* in_sizes, int n_in,
                              void* d_out, int out_size, void* d_ws, size_t ws_size,
                              hipStream_t stream) {
  const float* x      = (const float*)d_in[0];
  const float* h0     = (const float*)d_in[1];
  const float* w_ih0  = (const float*)d_in[2];
  const float* w_hh0  = (const float*)d_in[3];
  const float* b_ih0  = (const float*)d_in[4];
  const float* b_hh0  = (const float*)d_in[5];
  const float* w_ih12 = (const float*)d_in[6];
  const float* w_hh12 = (const float*)d_in[7];
  const float* b_ih12 = (const float*)d_in[8];
  const float* b_hh12 = (const float*)d_in[9];
  float* out = (float*)d_out;
  int* flags = (int*)d_ws;

  hipLaunchKernelGGL(init_flags, dim3(1), dim3(256), 0, stream, flags);
  hipLaunchKernelGGL(gemm_gx, dim3(768), dim3(256), 0, stream, x, w_ih0, b_ih0, out);
  hipLaunchKernelGGL(scan_gru, dim3(256), dim3(256), 0, stream,
                     h0, w_hh0, b_hh0, w_ih12, w_hh12, b_ih12, b_hh12, out, flags, x);
}

// Round 3
// 9423.772 us; speedup vs baseline: 1.0998x; 1.0998x over previous
//
#include <hip/hip_runtime.h>

#define LSEQ 2048
#define NB 24
#define NH 75
#define G3 225
#define NIN 500
#define OUTW 450
#define LAG 4

typedef _Float16 h2 __attribute__((ext_vector_type(2)));
typedef _Float16 h8 __attribute__((ext_vector_type(8)));
typedef float f4 __attribute__((ext_vector_type(4)));

// cvt_pkrtz returns __fp16-based vec2 on this clang; bit-cast to _Float16 vec2
__device__ __forceinline__ h2 pkrtz(float a, float b) {
  return __builtin_bit_cast(h2, __builtin_amdgcn_cvt_pkrtz(a, b));
}

__device__ __forceinline__ float dot2(h2 a, h2 b, float c) {
#if __has_builtin(__builtin_amdgcn_fdot2)
  return __builtin_amdgcn_fdot2(a, b, c, false);
#else
  return c + (float)a[0] * (float)b[0] + (float)a[1] * (float)b[1];
#endif
}

// 8-wide half dot via 4 fdot2 on sub-pairs (consecutive halves share a VGPR)
__device__ __forceinline__ float dot8(h8 w, h8 x, float c) {
  h2 w0{w[0], w[1]}, w1{w[2], w[3]}, w2{w[4], w[5]}, w3{w[6], w[7]};
  h2 x0{x[0], x[1]}, x1{x[2], x[3]}, x2{x[4], x[5]}, x3{x[6], x[7]};
  c = dot2(w0, x0, c);
  c = dot2(w1, x1, c);
  c = dot2(w2, x2, c);
  c = dot2(w3, x3, c);
  return c;
}

// load 8 floats (guarded) -> h8
__device__ __forceinline__ h8 ld8f(const float* p, int base, int n) {
  h8 o;
#pragma unroll
  for (int i = 0; i < 8; i += 2) {
    float a = (base + i < n) ? p[base + i] : 0.f;
    float b = (base + i + 1 < n) ? p[base + i + 1] : 0.f;
    h2 t = pkrtz(a, b);
    o[i] = t[0];
    o[i + 1] = t[1];
  }
  return o;
}

__device__ __forceinline__ h8 zero8() {
  h8 v;
#pragma unroll
  for (int i = 0; i < 8; i++) v[i] = (_Float16)0;
  return v;
}

__device__ __forceinline__ float sigm(float x) {
  return __builtin_amdgcn_rcpf(1.f + __builtin_amdgcn_exp2f(-1.4426950408889634f * x));
}
__device__ __forceinline__ float tanh_f(float x) {
  float xx = fminf(x, 15.f);
  float e = __builtin_amdgcn_exp2f(2.8853900817779268f * xx);
  return (e - 1.f) * __builtin_amdgcn_rcpf(e + 1.f);
}

// ---------------- init: zero the progress flags in d_ws ----------------
__global__ void init_flags(int* f) {
  if (threadIdx.x < 144) f[threadIdx.x] = 0;
}

// ---------------- kernel A: gx = x @ w_ih0^T + b_ih0, f16-packed into out cols [225:450) ----
__device__ __forceinline__ void load8_guard(float* v, const float* src, int kbase, bool rowvalid) {
  if (rowvalid && (kbase + 8 <= NIN)) {
    f4 t0 = *(const f4*)(src);
    f4 t1 = *(const f4*)(src + 4);
    v[0] = t0[0]; v[1] = t0[1]; v[2] = t0[2]; v[3] = t0[3];
    v[4] = t1[0]; v[5] = t1[1]; v[6] = t1[2]; v[7] = t1[3];
  } else {
#pragma unroll
    for (int i = 0; i < 8; i++) v[i] = (rowvalid && (kbase + i < NIN)) ? src[i] : 0.f;
  }
}

__device__ __forceinline__ void pack8_store(_Float16* dst, const float* v) {
  h2 a = pkrtz(v[0], v[1]);
  h2 b = pkrtz(v[2], v[3]);
  h2 c = pkrtz(v[4], v[5]);
  h2 d = pkrtz(v[6], v[7]);
  h8 o;
  o[0] = a[0]; o[1] = a[1]; o[2] = b[0]; o[3] = b[1];
  o[4] = c[0]; o[5] = c[1]; o[6] = d[0]; o[7] = d[1];
  *(h8*)dst = o;
}

__global__ __launch_bounds__(256) void gemm_gx(const float* __restrict__ x,
                                               const float* __restrict__ w,
                                               const float* __restrict__ bias,
                                               float* __restrict__ out) {
  __shared__ __align__(16) _Float16 xs[64 * 40];
  __shared__ __align__(16) _Float16 wsh[464 * 40];

  const int tid = threadIdx.x;
  const int blk = blockIdx.x;
  const int lane = tid & 63, wid = tid >> 6;
  const int q = lane >> 4, cn = lane & 15;
  const int r = tid >> 2, kq = tid & 3;

  f4 acc[29];
#pragma unroll
  for (int j = 0; j < 29; j++) acc[j] = f4{0.f, 0.f, 0.f, 0.f};

  for (int kc = 0; kc < 16; kc++) {
    const int kbase = kc * 32 + kq * 8;
    {
      const float* src = x + (size_t)(blk * 64 + r) * NIN + kbase;
      float v[8];
      load8_guard(v, src, kbase, true);
      pack8_store(&xs[r * 40 + kq * 8], v);
    }
#pragma unroll
    for (int it = 0; it < 8; it++) {
      int rr = r + it * 64;
      if (rr < 464) {
        const float* src = w + (size_t)rr * NIN + kbase;
        float v[8];
        load8_guard(v, src, kbase, rr < OUTW);
        pack8_store(&wsh[rr * 40 + kq * 8], v);
      }
    }
    __syncthreads();
    h8 a = *(const h8*)&xs[(wid * 16 + cn) * 40 + q * 8];
#pragma unroll
    for (int j = 0; j < 29; j++) {
      h8 bf = *(const h8*)&wsh[(j * 16 + cn) * 40 + q * 8];
      acc[j] = __builtin_amdgcn_mfma_f32_16x16x32_f16(a, bf, acc[j], 0, 0, 0);
    }
    __syncthreads();
  }

#pragma unroll
  for (int j = 0; j < 29; j++) {
    int n = j * 16 + cn;
    float bv = (n < OUTW) ? bias[n] : 0.f;
#pragma unroll
    for (int rr = 0; rr < 4; rr++) {
      float val = acc[j][rr] + bv;
      float partner = __shfl_xor(val, 1, 64);
      if (((lane & 1) == 0) && n < OUTW) {
        h2 pk = pkrtz(val, partner);
        int mg = blk * 64 + wid * 16 + q * 4 + rr;
        out[(size_t)mg * OUTW + G3 + (n >> 1)] = __builtin_bit_cast(float, pk);
      }
    }
  }
}

// ---------------- kernel B: pipelined persistent GRU scan ----------------
// 144 WGs = cell (0..5) x batch (0..23). Weights in NAMED h8 register variables
// (no arrays -> no scratch). Cross-cell handoff via d_out + agent-scope flags;
// spare lanes (225..255) run a 2-stage register pipeline: issue global loads of
// upstream h at step t for time t+LAG, commit to the LDS ring at step t+1.
__device__ __forceinline__ void wait_flags(int* flags, int i0, int i1, int want) {
  while (__hip_atomic_load(&flags[i0], __ATOMIC_ACQUIRE, __HIP_MEMORY_SCOPE_AGENT) < want ||
         __hip_atomic_load(&flags[i1], __ATOMIC_ACQUIRE, __HIP_MEMORY_SCOPE_AGENT) < want)
    __builtin_amdgcn_s_sleep(2);
}

__global__ __launch_bounds__(256, 1) __attribute__((amdgpu_waves_per_eu(1)))
void scan_gru(
    const float* __restrict__ h0,
    const float* __restrict__ w_hh0, const float* __restrict__ b_hh0,
    const float* __restrict__ w_ih12, const float* __restrict__ w_hh12,
    const float* __restrict__ b_ih12, const float* __restrict__ b_hh12,
    float* __restrict__ out, int* flags) {
  __shared__ float A_s[G3], B_s[G3];
  __shared__ __align__(16) _Float16 h16[80];      // 75 + zero pad
  __shared__ __align__(16) _Float16 xr[8][152];   // ring: 150 + zero pad per slot

  const int bi = blockIdx.x;
  if (bi >= 144) return;
  const int tid = threadIdx.x;

  const int c = bi / NB, b = bi % NB;
  const int l = c >> 1, d = c & 1;
  const int g = tid;
  const bool isg = tid < G3;
  const int u0 = (l - 1) * 2;  // upstream cell pair (valid for l>=1)

  // ---- weights as NAMED h8 registers (guaranteed non-scratch) ----
  h8 W0 = zero8(), W1 = zero8(), W2 = zero8(), W3 = zero8(), W4 = zero8();
  h8 W5 = zero8(), W6 = zero8(), W7 = zero8(), W8 = zero8(), W9 = zero8();
  h8 U0 = zero8(), U1 = zero8(), U2 = zero8(), U3 = zero8(), U4 = zero8();
  h8 U5 = zero8(), U6 = zero8(), U7 = zero8(), U8 = zero8(), U9 = zero8();
  h8 U10 = zero8(), U11 = zero8(), U12 = zero8(), U13 = zero8(), U14 = zero8();
  h8 U15 = zero8(), U16 = zero8(), U17 = zero8(), U18 = zero8();
  float bhh_g = 0.f, bih_g = 0.f;

  if (isg) {
    const float* whh = (l == 0) ? (w_hh0 + (size_t)(d * G3 + g) * NH)
                                : (w_hh12 + (size_t)(((l - 1) * 2 + d) * G3 + g) * NH);
    W0 = ld8f(whh, 0, NH);  W1 = ld8f(whh, 8, NH);  W2 = ld8f(whh, 16, NH);
    W3 = ld8f(whh, 24, NH); W4 = ld8f(whh, 32, NH); W5 = ld8f(whh, 40, NH);
    W6 = ld8f(whh, 48, NH); W7 = ld8f(whh, 56, NH); W8 = ld8f(whh, 64, NH);
    W9 = ld8f(whh, 72, NH);
    bhh_g = (l == 0) ? b_hh0[d * G3 + g] : b_hh12[((l - 1) * 2 + d) * G3 + g];
    if (l > 0) {
      const float* wih = w_ih12 + (size_t)(((l - 1) * 2 + d) * G3 + g) * (2 * NH);
      U0 = ld8f(wih, 0, 150);   U1 = ld8f(wih, 8, 150);   U2 = ld8f(wih, 16, 150);
      U3 = ld8f(wih, 24, 150);  U4 = ld8f(wih, 32, 150);  U5 = ld8f(wih, 40, 150);
      U6 = ld8f(wih, 48, 150);  U7 = ld8f(wih, 56, 150);  U8 = ld8f(wih, 64, 150);
      U9 = ld8f(wih, 72, 150);  U10 = ld8f(wih, 80, 150); U11 = ld8f(wih, 88, 150);
      U12 = ld8f(wih, 96, 150); U13 = ld8f(wih, 104, 150); U14 = ld8f(wih, 112, 150);
      U15 = ld8f(wih, 120, 150); U16 = ld8f(wih, 128, 150); U17 = ld8f(wih, 136, 150);
      U18 = ld8f(wih, 144, 150);
      bih_g = b_ih12[((l - 1) * 2 + d) * G3 + g];
    }
  }

  float hreg = 0.f;
  if (tid < NH) {
    hreg = h0[(size_t)(c * NB + b) * NH + tid];
    h16[tid] = (_Float16)hreg;
  }
  if (tid >= NH && tid < 80) h16[tid] = (_Float16)0;
  if (tid < 8) { xr[tid][150] = (_Float16)0; xr[tid][151] = (_Float16)0; }

  // prologue: fill ring slots 0..LAG-1 with upstream h (layers 1-2)
  if (l >= 1) {
    for (int p = 0; p < LAG; p++) {
      if (tid == 0) wait_flags(flags, u0 * NB + b, (u0 + 1) * NB + b, p + 1);
      __syncthreads();
      if (tid < NH) {
        const float* rp = out + ((size_t)p * NB + b) * OUTW + u0 * NH;
        ((h2*)xr[p])[tid] = pkrtz(rp[2 * tid], rp[2 * tid + 1]);
      }
    }
  }
  // layer-0: preload gx(t=0)
  float gx_cur = 0.f, gx_next = 0.f;
  if (l == 0 && isg) {
    int n = d * G3 + g;
    float s = out[(size_t)b * OUTW + G3 + (n >> 1)];
    h2 hh = __builtin_bit_cast(h2, s);
    gx_cur = (n & 1) ? (float)hh[1] : (float)hh[0];
  }
  __syncthreads();

  // spare-lane prefetch pipeline registers (named scalars)
  float pf0 = 0.f, pf1 = 0.f, pf2 = 0.f, pf3 = 0.f, pf4 = 0.f;
  const int i0 = (tid - G3) * 5;

  for (int t = 0; t < LSEQ; t++) {
    float* orow = out + ((size_t)t * NB + b) * OUTW;

    // ---- spare lanes (l>=1): commit previous loads, issue next loads ----
    if (l >= 1 && !isg) {
      int tprev = t + LAG - 1;  // loaded last step
      if (t > 0 && tprev < LSEQ) {
        _Float16* slot = xr[tprev & 7];
        if (i0 + 0 < 150) slot[i0 + 0] = (_Float16)pf0;
        if (i0 + 1 < 150) slot[i0 + 1] = (_Float16)pf1;
        if (i0 + 2 < 150) slot[i0 + 2] = (_Float16)pf2;
        if (i0 + 3 < 150) slot[i0 + 3] = (_Float16)pf3;
        if (i0 + 4 < 150) slot[i0 + 4] = (_Float16)pf4;
      }
      int tt = t + LAG;
      if (tt < LSEQ) {
        if (tid == G3) wait_flags(flags, u0 * NB + b, (u0 + 1) * NB + b, tt + 1);
        const float* rp = out + ((size_t)tt * NB + b) * OUTW + u0 * NH;
        pf0 = (i0 + 0 < 150) ? rp[i0 + 0] : 0.f;
        pf1 = (i0 + 1 < 150) ? rp[i0 + 1] : 0.f;
        pf2 = (i0 + 2 < 150) ? rp[i0 + 2] : 0.f;
        pf3 = (i0 + 3 < 150) ? rp[i0 + 3] : 0.f;
        pf4 = (i0 + 4 < 150) ? rp[i0 + 4] : 0.f;
      }
    }

    // ---- layer-0: issue gx(t+1) load early (latency hidden by dots) ----
    if (l == 0 && isg && (t + 1 < LSEQ)) {
      int n = d * G3 + g;
      float s = out[((size_t)(t + 1) * NB + b) * OUTW + G3 + (n >> 1)];
      h2 hh = __builtin_bit_cast(h2, s);
      gx_next = (n & 1) ? (float)hh[1] : (float)hh[0];
    }

    // ---- gate lanes: preactivations ----
    if (isg) {
      const h8* hv = (const h8*)h16;
      float b0 = bhh_g, b1 = 0.f, b2 = 0.f, b3 = 0.f;
      b0 = dot8(W0, hv[0], b0); b1 = dot8(W1, hv[1], b1);
      b2 = dot8(W2, hv[2], b2); b3 = dot8(W3, hv[3], b3);
      b0 = dot8(W4, hv[4], b0); b1 = dot8(W5, hv[5], b1);
      b2 = dot8(W6, hv[6], b2); b3 = dot8(W7, hv[7], b3);
      b0 = dot8(W8, hv[8], b0); b1 = dot8(W9, hv[9], b1);
      float accB = (b0 + b1) + (b2 + b3);
      float accA;
      if (l == 0) {
        accA = gx_cur;
      } else {
        const h8* xv = (const h8*)xr[t & 7];
        float a0 = bih_g, a1 = 0.f, a2 = 0.f, a3 = 0.f;
        a0 = dot8(U0, xv[0], a0);   a1 = dot8(U1, xv[1], a1);
        a2 = dot8(U2, xv[2], a2);   a3 = dot8(U3, xv[3], a3);
        a0 = dot8(U4, xv[4], a0);   a1 = dot8(U5, xv[5], a1);
        a2 = dot8(U6, xv[6], a2);   a3 = dot8(U7, xv[7], a3);
        a0 = dot8(U8, xv[8], a0);   a1 = dot8(U9, xv[9], a1);
        a2 = dot8(U10, xv[10], a2); a3 = dot8(U11, xv[11], a3);
        a0 = dot8(U12, xv[12], a0); a1 = dot8(U13, xv[13], a1);
        a2 = dot8(U14, xv[14], a2); a3 = dot8(U15, xv[15], a3);
        a0 = dot8(U16, xv[16], a0); a1 = dot8(U17, xv[17], a1);
        a2 = dot8(U18, xv[18], a2);
        accA = (a0 + a1) + (a2 + a3);
      }
      A_s[g] = accA;
      B_s[g] = accB;
    }
    __syncthreads();  // gates visible

    if (tid < NH) {
      int j = tid;
      float rg = sigm(A_s[j] + B_s[j]);
      float zg = sigm(A_s[NH + j] + B_s[NH + j]);
      float ng = tanh_f(A_s[2 * NH + j] + rg * B_s[2 * NH + j]);
      float hn = (1.f - zg) * ng + zg * hreg;
      hreg = hn;
      h16[j] = (_Float16)hn;
      orow[c * NH + j] = hn;
    }
    __syncthreads();  // h16 + out stores drained

    if (tid == 0 && c < 4)
      __hip_atomic_store(&flags[bi], t + 1, __ATOMIC_RELEASE, __HIP_MEMORY_SCOPE_AGENT);
    gx_cur = gx_next;
  }
}

extern "C" void kernel_launch(void* const* d_in, const int* in_sizes, int n_in,
                              void* d_out, int out_size, void* d_ws, size_t ws_size,
                              hipStream_t stream) {
  const float* x      = (const float*)d_in[0];
  const float* h0     = (const float*)d_in[1];
  const float* w_ih0  = (const float*)d_in[2];
  const float* w_hh0  = (const float*)d_in[3];
  const float* b_ih0  = (const float*)d_in[4];
  const float* b_hh0  = (const float*)d_in[5];
  const float* w_ih12 = (const float*)d_in[6];
  const float* w_hh12 = (const float*)d_in[7];
  const float* b_ih12 = (const float*)d_in[8];
  const float* b_hh12 = (const float*)d_in[9];
  float* out = (float*)d_out;
  int* flags = (int*)d_ws;

  hipLaunchKernelGGL(init_flags, dim3(1), dim3(256), 0, stream, flags);
  hipLaunchKernelGGL(gemm_gx, dim3(768), dim3(256), 0, stream, x, w_ih0, b_ih0, out);
  hipLaunchKernelGGL(scan_gru, dim3(144), dim3(256), 0, stream,
                     h0, w_hh0, b_hh0, w_ih12, w_hh12, b_ih12, b_hh12, out, flags);
}

// Round 4
// 4252.924 us; speedup vs baseline: 2.4370x; 2.2158x over previous
//
#include <hip/hip_runtime.h>

#define LSEQ 2048
#define NB 24
#define NH 75
#define G3 225
#define NIN 500
#define OUTW 450

typedef _Float16 h2 __attribute__((ext_vector_type(2)));
typedef _Float16 h8 __attribute__((ext_vector_type(8)));
typedef float f4 __attribute__((ext_vector_type(4)));

__device__ __forceinline__ h2 pkrtz(float a, float b) {
  return __builtin_bit_cast(h2, __builtin_amdgcn_cvt_pkrtz(a, b));
}
__device__ __forceinline__ float dot2(h2 a, h2 b, float c) {
  return __builtin_amdgcn_fdot2(a, b, c, false);
}
// 8-wide half dot: pairs align to dwords, so extracts are free sub-reg refs
__device__ __forceinline__ float dot8(h8 w, h8 x, float c) {
  h2 w0{w[0], w[1]}, w1{w[2], w[3]}, w2{w[4], w[5]}, w3{w[6], w[7]};
  h2 x0{x[0], x[1]}, x1{x[2], x[3]}, x2{x[4], x[5]}, x3{x[6], x[7]};
  c = dot2(w0, x0, c);
  c = dot2(w1, x1, c);
  c = dot2(w2, x2, c);
  c = dot2(w3, x3, c);
  return c;
}
__device__ __forceinline__ h8 ld8f(const float* p, int base, int n) {
  h8 o;
#pragma unroll
  for (int i = 0; i < 8; i += 2) {
    float a = (base + i < n) ? p[base + i] : 0.f;
    float b = (base + i + 1 < n) ? p[base + i + 1] : 0.f;
    h2 t = pkrtz(a, b);
    o[i] = t[0];
    o[i + 1] = t[1];
  }
  return o;
}
__device__ __forceinline__ h8 zero8() {
  h8 v;
#pragma unroll
  for (int i = 0; i < 8; i++) v[i] = (_Float16)0;
  return v;
}
__device__ __forceinline__ float sigm(float x) {
  return __builtin_amdgcn_rcpf(1.f + __builtin_amdgcn_exp2f(-1.4426950408889634f * x));
}
__device__ __forceinline__ float tanh_f(float x) {
  float xx = fminf(x, 15.f);
  float e = __builtin_amdgcn_exp2f(2.8853900817779268f * xx);
  return (e - 1.f) * __builtin_amdgcn_rcpf(e + 1.f);
}

// device-scope relaxed (sc1, no cache-maintenance ops)
__device__ __forceinline__ float ldg_dev(const float* p) {
  return __hip_atomic_load(p, __ATOMIC_RELAXED, __HIP_MEMORY_SCOPE_AGENT);
}
__device__ __forceinline__ void stg_dev(float* p, float v) {
  __hip_atomic_store(p, v, __ATOMIC_RELAXED, __HIP_MEMORY_SCOPE_AGENT);
}
__device__ __forceinline__ int ldflag(const int* p) {
  return __hip_atomic_load(p, __ATOMIC_RELAXED, __HIP_MEMORY_SCOPE_AGENT);
}
__device__ __forceinline__ void stflag(int* p, int v) {
  __hip_atomic_store(p, v, __ATOMIC_RELAXED, __HIP_MEMORY_SCOPE_AGENT);
}

#define PIN4(a, b, c, d) asm("" : "+v"(a), "+v"(b), "+v"(c), "+v"(d))
#define PIN2(a, b) asm("" : "+v"(a), "+v"(b))

// ---------------- init flags ----------------
__global__ void init_flags(int* f) {
  if (threadIdx.x < 144) stflag(&f[threadIdx.x], 0);
}

// ---------------- kernel A: gx GEMM (unchanged from R3, it works) ----------------
__device__ __forceinline__ void load8_guard(float* v, const float* src, int kbase, bool rowvalid) {
  if (rowvalid && (kbase + 8 <= NIN)) {
    f4 t0 = *(const f4*)(src);
    f4 t1 = *(const f4*)(src + 4);
    v[0] = t0[0]; v[1] = t0[1]; v[2] = t0[2]; v[3] = t0[3];
    v[4] = t1[0]; v[5] = t1[1]; v[6] = t1[2]; v[7] = t1[3];
  } else {
#pragma unroll
    for (int i = 0; i < 8; i++) v[i] = (rowvalid && (kbase + i < NIN)) ? src[i] : 0.f;
  }
}
__device__ __forceinline__ void pack8_store(_Float16* dst, const float* v) {
  h2 a = pkrtz(v[0], v[1]);
  h2 b = pkrtz(v[2], v[3]);
  h2 c = pkrtz(v[4], v[5]);
  h2 d = pkrtz(v[6], v[7]);
  h8 o;
  o[0] = a[0]; o[1] = a[1]; o[2] = b[0]; o[3] = b[1];
  o[4] = c[0]; o[5] = c[1]; o[6] = d[0]; o[7] = d[1];
  *(h8*)dst = o;
}

__global__ __launch_bounds__(256) void gemm_gx(const float* __restrict__ x,
                                               const float* __restrict__ w,
                                               const float* __restrict__ bias,
                                               float* __restrict__ out) {
  __shared__ __align__(16) _Float16 xs[64 * 40];
  __shared__ __align__(16) _Float16 wsh[464 * 40];
  const int tid = threadIdx.x;
  const int blk = blockIdx.x;
  const int lane = tid & 63, wid = tid >> 6;
  const int q = lane >> 4, cn = lane & 15;
  const int r = tid >> 2, kq = tid & 3;

  f4 acc[29];
#pragma unroll
  for (int j = 0; j < 29; j++) acc[j] = f4{0.f, 0.f, 0.f, 0.f};

  for (int kc = 0; kc < 16; kc++) {
    const int kbase = kc * 32 + kq * 8;
    {
      const float* src = x + (size_t)(blk * 64 + r) * NIN + kbase;
      float v[8];
      load8_guard(v, src, kbase, true);
      pack8_store(&xs[r * 40 + kq * 8], v);
    }
#pragma unroll
    for (int it = 0; it < 8; it++) {
      int rr = r + it * 64;
      if (rr < 464) {
        const float* src = w + (size_t)rr * NIN + kbase;
        float v[8];
        load8_guard(v, src, kbase, rr < OUTW);
        pack8_store(&wsh[rr * 40 + kq * 8], v);
      }
    }
    __syncthreads();
    h8 a = *(const h8*)&xs[(wid * 16 + cn) * 40 + q * 8];
#pragma unroll
    for (int j = 0; j < 29; j++) {
      h8 bf = *(const h8*)&wsh[(j * 16 + cn) * 40 + q * 8];
      acc[j] = __builtin_amdgcn_mfma_f32_16x16x32_f16(a, bf, acc[j], 0, 0, 0);
    }
    __syncthreads();
  }
#pragma unroll
  for (int j = 0; j < 29; j++) {
    int n = j * 16 + cn;
    float bv = (n < OUTW) ? bias[n] : 0.f;
#pragma unroll
    for (int rr = 0; rr < 4; rr++) {
      float val = acc[j][rr] + bv;
      float partner = __shfl_xor(val, 1, 64);
      if (((lane & 1) == 0) && n < OUTW) {
        h2 pk = pkrtz(val, partner);
        int mg = blk * 64 + wid * 16 + q * 4 + rr;
        out[(size_t)mg * OUTW + G3 + (n >> 1)] = __builtin_bit_cast(float, pk);
      }
    }
  }
}

// ---------------- kernel B: persistent GRU scan, batched relaxed-sc1 sync ----------------
// 144 WGs = cell c (0..5) x batch b (0..23), bi = c*24+b.
// Lanes: tid<128 gate lanes (rows 2t, 2t+1); tid 128..202 h-update; tid 208..237 sync.
// Cross-cell channel: h rows in `out` via relaxed device-scope (sc1) stores/loads,
// flags published every 4 steps. Consumer prefetch LAG=12, 16-slot LDS x-ring.
__global__ __launch_bounds__(256, 1) __attribute__((amdgpu_waves_per_eu(1)))
void scan_gru(const float* __restrict__ h0,
              const float* __restrict__ w_hh0, const float* __restrict__ b_hh0,
              const float* __restrict__ w_ih12, const float* __restrict__ w_hh12,
              const float* __restrict__ b_ih12, const float* __restrict__ b_hh12,
              float* __restrict__ out, int* flags) {
  __shared__ __align__(16) float A_s[232], B_s[232];
  __shared__ __align__(16) _Float16 h16[80];
  __shared__ __align__(16) _Float16 xr[16][152];

  const int bi = blockIdx.x;
  if (bi >= 144) return;
  const int tid = threadIdx.x;
  const int c = bi / NB, b = bi % NB;
  const int l = c >> 1, d = c & 1;
  const int ci = (l - 1) * 2 + d;   // index into *_12 arrays (l>=1)
  const int u0 = (l - 1) * 2;       // upstream cell pair

  const int r0 = tid * 2;
  const int r0c = (r0 < G3) ? r0 : G3 - 1;
  const int r1c = (r0 + 1 < G3) ? r0 + 1 : G3 - 1;
  const bool isgate = (tid < 128);
  const int hj = tid - 128;
  const bool ish = (hj >= 0) && (hj < NH);
  const int s = tid - 208;
  const bool issync = (s >= 0) && (s < 30) && (l >= 1);

  // ---- weights, 2 rows per gate lane, named h8 regs ----
  h8 Wa0 = zero8(), Wa1 = zero8(), Wa2 = zero8(), Wa3 = zero8(), Wa4 = zero8();
  h8 Wa5 = zero8(), Wa6 = zero8(), Wa7 = zero8(), Wa8 = zero8(), Wa9 = zero8();
  h8 Wb0 = zero8(), Wb1 = zero8(), Wb2 = zero8(), Wb3 = zero8(), Wb4 = zero8();
  h8 Wb5 = zero8(), Wb6 = zero8(), Wb7 = zero8(), Wb8 = zero8(), Wb9 = zero8();
  h8 Ua0 = zero8(), Ua1 = zero8(), Ua2 = zero8(), Ua3 = zero8(), Ua4 = zero8();
  h8 Ua5 = zero8(), Ua6 = zero8(), Ua7 = zero8(), Ua8 = zero8(), Ua9 = zero8();
  h8 Ua10 = zero8(), Ua11 = zero8(), Ua12 = zero8(), Ua13 = zero8(), Ua14 = zero8();
  h8 Ua15 = zero8(), Ua16 = zero8(), Ua17 = zero8(), Ua18 = zero8();
  h8 Ub0 = zero8(), Ub1 = zero8(), Ub2 = zero8(), Ub3 = zero8(), Ub4 = zero8();
  h8 Ub5 = zero8(), Ub6 = zero8(), Ub7 = zero8(), Ub8 = zero8(), Ub9 = zero8();
  h8 Ub10 = zero8(), Ub11 = zero8(), Ub12 = zero8(), Ub13 = zero8(), Ub14 = zero8();
  h8 Ub15 = zero8(), Ub16 = zero8(), Ub17 = zero8(), Ub18 = zero8();
  float bhha = 0.f, bhhb = 0.f, biha = 0.f, bihb = 0.f;

  if (isgate) {
    const float* wA = (l == 0) ? w_hh0 + (size_t)(d * G3 + r0c) * NH
                               : w_hh12 + (size_t)(ci * G3 + r0c) * NH;
    const float* wB = (l == 0) ? w_hh0 + (size_t)(d * G3 + r1c) * NH
                               : w_hh12 + (size_t)(ci * G3 + r1c) * NH;
    Wa0 = ld8f(wA, 0, NH);  Wa1 = ld8f(wA, 8, NH);  Wa2 = ld8f(wA, 16, NH);
    Wa3 = ld8f(wA, 24, NH); Wa4 = ld8f(wA, 32, NH); Wa5 = ld8f(wA, 40, NH);
    Wa6 = ld8f(wA, 48, NH); Wa7 = ld8f(wA, 56, NH); Wa8 = ld8f(wA, 64, NH);
    Wa9 = ld8f(wA, 72, NH);
    Wb0 = ld8f(wB, 0, NH);  Wb1 = ld8f(wB, 8, NH);  Wb2 = ld8f(wB, 16, NH);
    Wb3 = ld8f(wB, 24, NH); Wb4 = ld8f(wB, 32, NH); Wb5 = ld8f(wB, 40, NH);
    Wb6 = ld8f(wB, 48, NH); Wb7 = ld8f(wB, 56, NH); Wb8 = ld8f(wB, 64, NH);
    Wb9 = ld8f(wB, 72, NH);
    bhha = (l == 0) ? b_hh0[d * G3 + r0c] : b_hh12[ci * G3 + r0c];
    bhhb = (l == 0) ? b_hh0[d * G3 + r1c] : b_hh12[ci * G3 + r1c];
    if (l > 0) {
      const float* uA = w_ih12 + (size_t)(ci * G3 + r0c) * (2 * NH);
      const float* uB = w_ih12 + (size_t)(ci * G3 + r1c) * (2 * NH);
      Ua0 = ld8f(uA, 0, 150);   Ua1 = ld8f(uA, 8, 150);   Ua2 = ld8f(uA, 16, 150);
      Ua3 = ld8f(uA, 24, 150);  Ua4 = ld8f(uA, 32, 150);  Ua5 = ld8f(uA, 40, 150);
      Ua6 = ld8f(uA, 48, 150);  Ua7 = ld8f(uA, 56, 150);  Ua8 = ld8f(uA, 64, 150);
      Ua9 = ld8f(uA, 72, 150);  Ua10 = ld8f(uA, 80, 150); Ua11 = ld8f(uA, 88, 150);
      Ua12 = ld8f(uA, 96, 150); Ua13 = ld8f(uA, 104, 150); Ua14 = ld8f(uA, 112, 150);
      Ua15 = ld8f(uA, 120, 150); Ua16 = ld8f(uA, 128, 150); Ua17 = ld8f(uA, 136, 150);
      Ua18 = ld8f(uA, 144, 150);
      Ub0 = ld8f(uB, 0, 150);   Ub1 = ld8f(uB, 8, 150);   Ub2 = ld8f(uB, 16, 150);
      Ub3 = ld8f(uB, 24, 150);  Ub4 = ld8f(uB, 32, 150);  Ub5 = ld8f(uB, 40, 150);
      Ub6 = ld8f(uB, 48, 150);  Ub7 = ld8f(uB, 56, 150);  Ub8 = ld8f(uB, 64, 150);
      Ub9 = ld8f(uB, 72, 150);  Ub10 = ld8f(uB, 80, 150); Ub11 = ld8f(uB, 88, 150);
      Ub12 = ld8f(uB, 96, 150); Ub13 = ld8f(uB, 104, 150); Ub14 = ld8f(uB, 112, 150);
      Ub15 = ld8f(uB, 120, 150); Ub16 = ld8f(uB, 128, 150); Ub17 = ld8f(uB, 136, 150);
      Ub18 = ld8f(uB, 144, 150);
      biha = b_ih12[ci * G3 + r0c];
      bihb = b_ih12[ci * G3 + r1c];
    }
  }

  float hreg = 0.f, hh0 = 0.f, hh1 = 0.f, hh2 = 0.f;
  if (ish) {
    hreg = h0[(size_t)(c * NB + b) * NH + hj];
    h16[hj] = (_Float16)hreg;
  }
  if (tid >= 203 && tid < 208) h16[NH + (tid - 203)] = (_Float16)0;
  if (tid < 16) { xr[tid][150] = (_Float16)0; xr[tid][151] = (_Float16)0; }

  // prologue: consumer ring fill, times 0..11 (batches 0..2), then pre-verify flag>=16
  if (issync) {
    const int* f0 = &flags[u0 * NB + b];
    const int* f1 = &flags[(u0 + 1) * NB + b];
    for (int p = 0; p < 3; p++) {
      while (ldflag(f0) < 4 * p + 4 || ldflag(f1) < 4 * p + 4) {}
#pragma unroll
      for (int i = 0; i < 20; i++) {
        int q = s * 20 + i;
        int tt = 4 * p + q / 150;
        int rem = q % 150;
        float v = ldg_dev(&out[((size_t)tt * NB + b) * OUTW + u0 * NH + rem]);
        xr[tt & 15][rem] = (_Float16)v;
      }
    }
    while (ldflag(f0) < 16 || ldflag(f1) < 16) {}
  }

  // prologue: layer-0 gx(0)
  float gxc0 = 0.f, gxc1 = 0.f, gxn0 = 0.f, gxn1 = 0.f;
  if (l == 0 && tid < 113) {
    int n0 = d * G3 + r0;
    const float* row = out + (size_t)b * OUTW + G3;
    float s0 = row[n0 >> 1];
    float s1 = (d == 1) ? row[(n0 + 1) >> 1] : s0;
    h2 p0 = __builtin_bit_cast(h2, s0);
    h2 p1 = __builtin_bit_cast(h2, s1);
    gxc0 = (n0 & 1) ? (float)p0[1] : (float)p0[0];
    gxc1 = ((n0 + 1) & 1) ? (float)p1[1] : (float)p1[0];
  }
  __syncthreads();

  f4 P[5];  // sync-lane prefetch regs (const-indexed only)
#pragma unroll
  for (int i = 0; i < 5; i++) P[i] = f4{0.f, 0.f, 0.f, 0.f};

  for (int t = 0; t < LSEQ; t++) {
    // ================= P1 =================
    if (isgate) {
      // keep weights register-resident (defeat remat/reload)
      PIN4(Wa0, Wa1, Wa2, Wa3); PIN4(Wa4, Wa5, Wa6, Wa7); PIN2(Wa8, Wa9);
      PIN4(Wb0, Wb1, Wb2, Wb3); PIN4(Wb4, Wb5, Wb6, Wb7); PIN2(Wb8, Wb9);
      if (l > 0) {
        PIN4(Ua0, Ua1, Ua2, Ua3); PIN4(Ua4, Ua5, Ua6, Ua7); PIN4(Ua8, Ua9, Ua10, Ua11);
        PIN4(Ua12, Ua13, Ua14, Ua15); PIN2(Ua16, Ua17); asm("" : "+v"(Ua18));
        PIN4(Ub0, Ub1, Ub2, Ub3); PIN4(Ub4, Ub5, Ub6, Ub7); PIN4(Ub8, Ub9, Ub10, Ub11);
        PIN4(Ub12, Ub13, Ub14, Ub15); PIN2(Ub16, Ub17); asm("" : "+v"(Ub18));
      }
      const h8* hv = (const h8*)h16;
      h8 H0 = hv[0], H1 = hv[1], H2 = hv[2], H3 = hv[3], H4 = hv[4];
      h8 H5 = hv[5], H6 = hv[6], H7 = hv[7], H8 = hv[8], H9 = hv[9];
      float b0a = dot8(Wa0, H0, bhha), b0b = dot8(Wa1, H1, 0.f);
      b0a = dot8(Wa2, H2, b0a); b0b = dot8(Wa3, H3, b0b);
      b0a = dot8(Wa4, H4, b0a); b0b = dot8(Wa5, H5, b0b);
      b0a = dot8(Wa6, H6, b0a); b0b = dot8(Wa7, H7, b0b);
      b0a = dot8(Wa8, H8, b0a); b0b = dot8(Wa9, H9, b0b);
      float b1a = dot8(Wb0, H0, bhhb), b1b = dot8(Wb1, H1, 0.f);
      b1a = dot8(Wb2, H2, b1a); b1b = dot8(Wb3, H3, b1b);
      b1a = dot8(Wb4, H4, b1a); b1b = dot8(Wb5, H5, b1b);
      b1a = dot8(Wb6, H6, b1a); b1b = dot8(Wb7, H7, b1b);
      b1a = dot8(Wb8, H8, b1a); b1b = dot8(Wb9, H9, b1b);
      float accB0 = b0a + b0b, accB1 = b1a + b1b;
      float accA0, accA1;
      if (l == 0) {
        accA0 = gxc0;
        accA1 = gxc1;
      } else {
        const h8* xv = (const h8*)xr[t & 15];
        h8 X0 = xv[0], X1 = xv[1], X2 = xv[2], X3 = xv[3], X4 = xv[4];
        h8 X5 = xv[5], X6 = xv[6], X7 = xv[7], X8 = xv[8], X9 = xv[9];
        h8 X10 = xv[10], X11 = xv[11], X12 = xv[12], X13 = xv[13], X14 = xv[14];
        h8 X15 = xv[15], X16 = xv[16], X17 = xv[17], X18 = xv[18];
        float a0a = dot8(Ua0, X0, biha), a0b = dot8(Ua1, X1, 0.f);
        a0a = dot8(Ua2, X2, a0a);   a0b = dot8(Ua3, X3, a0b);
        a0a = dot8(Ua4, X4, a0a);   a0b = dot8(Ua5, X5, a0b);
        a0a = dot8(Ua6, X6, a0a);   a0b = dot8(Ua7, X7, a0b);
        a0a = dot8(Ua8, X8, a0a);   a0b = dot8(Ua9, X9, a0b);
        a0a = dot8(Ua10, X10, a0a); a0b = dot8(Ua11, X11, a0b);
        a0a = dot8(Ua12, X12, a0a); a0b = dot8(Ua13, X13, a0b);
        a0a = dot8(Ua14, X14, a0a); a0b = dot8(Ua15, X15, a0b);
        a0a = dot8(Ua16, X16, a0a); a0b = dot8(Ua17, X17, a0b);
        a0a = dot8(Ua18, X18, a0a);
        float a1a = dot8(Ub0, X0, bihb), a1b = dot8(Ub1, X1, 0.f);
        a1a = dot8(Ub2, X2, a1a);   a1b = dot8(Ub3, X3, a1b);
        a1a = dot8(Ub4, X4, a1a);   a1b = dot8(Ub5, X5, a1b);
        a1a = dot8(Ub6, X6, a1a);   a1b = dot8(Ub7, X7, a1b);
        a1a = dot8(Ub8, X8, a1a);   a1b = dot8(Ub9, X9, a1b);
        a1a = dot8(Ub10, X10, a1a); a1b = dot8(Ub11, X11, a1b);
        a1a = dot8(Ub12, X12, a1a); a1b = dot8(Ub13, X13, a1b);
        a1a = dot8(Ub14, X14, a1a); a1b = dot8(Ub15, X15, a1b);
        a1a = dot8(Ub16, X16, a1a); a1b = dot8(Ub17, X17, a1b);
        a1a = dot8(Ub18, X18, a1a);
        accA0 = a0a + a0b;
        accA1 = a1a + a1b;
      }
      if (tid < 112) {
        *(float2*)(A_s + r0) = make_float2(accA0, accA1);
        *(float2*)(B_s + r0) = make_float2(accB0, accB1);
      } else if (tid == 112) {
        A_s[224] = accA0;
        B_s[224] = accB0;
      }
      // layer-0: prefetch gx(t+1), hidden behind the dots/barrier
      if (l == 0 && tid < 113 && (t + 1 < LSEQ)) {
        int n0 = d * G3 + r0;
        const float* row = out + ((size_t)(t + 1) * NB + b) * OUTW + G3;
        float s0 = row[n0 >> 1];
        float s1 = (d == 1) ? row[(n0 + 1) >> 1] : s0;
        h2 p0 = __builtin_bit_cast(h2, s0);
        h2 p1 = __builtin_bit_cast(h2, s1);
        gxn0 = (n0 & 1) ? (float)p0[1] : (float)p0[0];
        gxn1 = ((n0 + 1) & 1) ? (float)p1[1] : (float)p1[0];
      }
    }
    if (issync && (t & 3) == 0) {
      // loads for times t+12..t+15 (flag pre-verified at t-4 / prologue)
      if (t + 12 < LSEQ) {
#pragma unroll
        for (int i = 0; i < 20; i++) {
          int q = s * 20 + i;
          int tt = t + 12 + q / 150;
          int rem = q % 150;
          P[i / 4][i % 4] = ldg_dev(&out[((size_t)tt * NB + b) * OUTW + u0 * NH + rem]);
        }
      }
      // pipelined check for the NEXT batch (consumed at t+4)
      if (t + 20 <= LSEQ) {
        const int* f0 = &flags[u0 * NB + b];
        const int* f1 = &flags[(u0 + 1) * NB + b];
        int need = t + 20;
        while (ldflag(f0) < need || ldflag(f1) < need) {}
      }
    }
    if (tid == 0 && c < 4 && (t & 3) == 0 && t > 0) stflag(&flags[c * NB + b], t);
    __syncthreads();  // barrier1 (implicit vmcnt drain orders stores before flag next iter)

    // ================= P2 =================
    if (ish) {
      float rg = sigm(A_s[hj] + B_s[hj]);
      float zg = sigm(A_s[NH + hj] + B_s[NH + hj]);
      float ng = tanh_f(A_s[2 * NH + hj] + rg * B_s[2 * NH + hj]);
      float hn = (1.f - zg) * ng + zg * hreg;
      hreg = hn;
      h16[hj] = (_Float16)hn;
      hh0 = ((t & 3) == 0) ? hn : hh0;
      hh1 = ((t & 3) == 1) ? hn : hh1;
      hh2 = ((t & 3) == 2) ? hn : hh2;
      if ((t & 3) == 3) {
        float* base = out + (size_t)(t - 3) * NB * OUTW + (size_t)b * OUTW + c * NH + hj;
        stg_dev(base, hh0);
        stg_dev(base + (size_t)NB * OUTW, hh1);
        stg_dev(base + 2 * (size_t)NB * OUTW, hh2);
        stg_dev(base + 3 * (size_t)NB * OUTW, hn);
      }
    }
    if (issync && (t & 3) == 0 && t + 12 < LSEQ) {
#pragma unroll
      for (int i = 0; i < 20; i++) {
        int q = s * 20 + i;
        int tt = t + 12 + q / 150;
        int rem = q % 150;
        xr[tt & 15][rem] = (_Float16)P[i / 4][i % 4];
      }
    }
    __syncthreads();  // barrier2 (drains batched sc1 h-stores before flag publish)
    gxc0 = gxn0;
    gxc1 = gxn1;
  }
  if (tid == 0 && c < 4) stflag(&flags[c * NB + b], LSEQ);
}

extern "C" void kernel_launch(void* const* d_in, const int* in_sizes, int n_in,
                              void* d_out, int out_size, void* d_ws, size_t ws_size,
                              hipStream_t stream) {
  const float* x      = (const float*)d_in[0];
  const float* h0     = (const float*)d_in[1];
  const float* w_ih0  = (const float*)d_in[2];
  const float* w_hh0  = (const float*)d_in[3];
  const float* b_ih0  = (const float*)d_in[4];
  const float* b_hh0  = (const float*)d_in[5];
  const float* w_ih12 = (const float*)d_in[6];
  const float* w_hh12 = (const float*)d_in[7];
  const float* b_ih12 = (const float*)d_in[8];
  const float* b_hh12 = (const float*)d_in[9];
  float* out = (float*)d_out;
  int* flags = (int*)d_ws;

  hipLaunchKernelGGL(init_flags, dim3(1), dim3(256), 0, stream, flags);
  hipLaunchKernelGGL(gemm_gx, dim3(768), dim3(256), 0, stream, x, w_ih0, b_ih0, out);
  hipLaunchKernelGGL(scan_gru, dim3(144), dim3(256), 0, stream,
                     h0, w_hh0, b_hh0, w_ih12, w_hh12, b_ih12, b_hh12, out, flags);
}